// Round 10
// baseline (215.941 us; speedup 1.0000x reference)
//
#include <hip/hip_runtime.h>
#include <hip/hip_fp16.h>

#define DM   1024
#define NH   16
#define HD   64
#define BATCH 4
#define SEQ  2048
#define MROWS (BATCH*SEQ)            // 8192
#define BHSD  ((size_t)BATCH*NH*SEQ*HD)  // 8388608 elems

using f32x4 = __attribute__((ext_vector_type(4))) float;
using f16x8 = __attribute__((ext_vector_type(8))) _Float16;
using f16x4 = __attribute__((ext_vector_type(4))) _Float16;
using fp16x2 = __attribute__((ext_vector_type(2))) __fp16;
using u32x2 = __attribute__((ext_vector_type(2))) unsigned int;

__device__ __forceinline__ void gload_lds16(const void* g, void* l) {
    __builtin_amdgcn_global_load_lds(
        (const __attribute__((address_space(1))) void*)g,
        (__attribute__((address_space(3))) void*)l, 16, 0, 0);
}

// ---- VALU-pipe cross-lane reduces via permlane*_swap builtins (no LDS-pipe traffic) ----
__device__ __forceinline__ float red16_max(float v) {
    u32x2 r = __builtin_amdgcn_permlane16_swap(__float_as_uint(v), __float_as_uint(v), false, false);
    return fmaxf(__uint_as_float(r[0]), __uint_as_float(r[1]));
}
__device__ __forceinline__ float red32_max(float v) {
    u32x2 r = __builtin_amdgcn_permlane32_swap(__float_as_uint(v), __float_as_uint(v), false, false);
    return fmaxf(__uint_as_float(r[0]), __uint_as_float(r[1]));
}
__device__ __forceinline__ float red16_add(float v) {
    u32x2 r = __builtin_amdgcn_permlane16_swap(__float_as_uint(v), __float_as_uint(v), false, false);
    return __uint_as_float(r[0]) + __uint_as_float(r[1]);
}
__device__ __forceinline__ float red32_add(float v) {
    u32x2 r = __builtin_amdgcn_permlane32_swap(__float_as_uint(v), __float_as_uint(v), false, false);
    return __uint_as_float(r[0]) + __uint_as_float(r[1]);
}

// ---------------- fp32 -> fp16 cast ----------------
__global__ __launch_bounds__(256) void f32_to_f16(const float* __restrict__ in,
                                                  _Float16* __restrict__ out, int n) {
    int i = (blockIdx.x * 256 + threadIdx.x) * 4;
    if (i >= n) return;
    float4 v = *(const float4*)(in + i);
    union { _Float16 h[4]; ushort4 u; } cv;
    cv.h[0] = (_Float16)v.x; cv.h[1] = (_Float16)v.y;
    cv.h[2] = (_Float16)v.z; cv.h[3] = (_Float16)v.w;
    *(ushort4*)(out + i) = cv.u;
}

// ---------------- RoPE cos/sin table: [SEQ][32] float2 ----------------
__global__ __launch_bounds__(256) void rope_table(const int* __restrict__ pos,
                                                  float2* __restrict__ tab) {
    int idx = blockIdx.x * 256 + threadIdx.x;    // 65536
    int s = idx >> 5, j = idx & 31;
    float p = (float)pos[s];
    float invf = powf(10000.0f, -(float)j / 32.0f);
    float ang = p * invf;
    tab[idx] = make_float2(cosf(ang), sinf(ang));
}

// ---------------- GEMM: C = A(MxK) * W^T, W row-major (N x K) ----------------
// BM=256, BN=128, BK=32, 4 waves, wave-tile 128x64 (acc 8x4): 12 ds_read per
// 32 MFMA (ratio 0.375) so the LDS pipe is no longer the binding pipe.
// 2-buffer double-buffering (cur = kt&1, provably-distinct), 48 KB LDS ->
// 3 blocks/CU co-resident to cover the barrier drain.
// MODE 0: fp32 out.  MODE 1: RoPE epilogue -> q,k [B][H][S][D], V^T [B][H][D][S];
//         Q pre-scaled by 0.125*log2(e) so attention uses exp2.
template<int MODE>
__global__ __launch_bounds__(256, 2)
void gemmT(const _Float16* __restrict__ A, const _Float16* __restrict__ Bw,
           float* __restrict__ outF, _Float16* __restrict__ qkv,
           const float2* __restrict__ rope) {
    constexpr int NK = DM / 32;                    // 32 K-tiles
    __shared__ __align__(16) _Float16 ldsA[2][256][32];   // 32 KB
    __shared__ __align__(16) _Float16 ldsB[2][128][32];   // 16 KB
    const int tid  = threadIdx.x;
    const int lane = tid & 63;
    const int wid  = tid >> 6;                     // 0..3
    const int m0 = blockIdx.x * 256;
    const int n0 = blockIdx.y * 128;
    const int wm = (wid >> 1) * 128;               // 2 wave-rows of 128
    const int wn = (wid & 1) * 64;                 // 2 wave-cols of 64
    const int g   = lane >> 4;
    const int r16 = lane & 15;

    // staging: unit u -> row = u>>2, phys chunk u&3 holds logical chunk
    // (u&3)^((row>>1)&3); source pre-swizzled, LDS dest linear. (R8-proven)
    const _Float16* srcA[4];
    int dstA[4];
    #pragma unroll
    for (int L = 0; L < 4; ++L) {
        const int u = L*256 + tid, row = u >> 2, c = (u & 3) ^ ((row >> 1) & 3);
        srcA[L] = A + (size_t)(m0 + row)*DM + c*8;
        dstA[L] = u*8;
    }
    const _Float16* srcB[2];
    int dstB[2];
    #pragma unroll
    for (int L = 0; L < 2; ++L) {
        const int u = L*256 + tid, row = u >> 2, c = (u & 3) ^ ((row >> 1) & 3);
        srcB[L] = Bw + (size_t)(n0 + row)*DM + c*8;
        dstB[L] = u*8;
    }

    #define STAGE(buf, kt) do {                                        \
        const int ko = (kt)*32;                                        \
        _Float16* bA = &ldsA[(buf)][0][0];                             \
        _Float16* bB = &ldsB[(buf)][0][0];                             \
        gload_lds16(srcA[0] + ko, bA + dstA[0]);                       \
        gload_lds16(srcA[1] + ko, bA + dstA[1]);                       \
        gload_lds16(srcA[2] + ko, bA + dstA[2]);                       \
        gload_lds16(srcA[3] + ko, bA + dstA[3]);                       \
        gload_lds16(srcB[0] + ko, bB + dstB[0]);                       \
        gload_lds16(srcB[1] + ko, bB + dstB[1]);                       \
    } while (0)

    f32x4 acc[8][4] = {};

    STAGE(0, 0);
    for (int kt = 0; kt < NK; ++kt) {
        __syncthreads();                           // buf[kt&1] ready; other free
        if (kt + 1 < NK) STAGE((kt + 1) & 1, kt + 1);
        const int buf = kt & 1;
        f16x8 af[8], bf[4];
        #pragma unroll
        for (int i = 0; i < 8; ++i) {
            int row = wm + i*16 + r16;
            af[i] = *(const f16x8*)&ldsA[buf][row][(g ^ ((row >> 1) & 3)) * 8];
        }
        #pragma unroll
        for (int j = 0; j < 4; ++j) {
            int row = wn + j*16 + r16;
            bf[j] = *(const f16x8*)&ldsB[buf][row][(g ^ ((row >> 1) & 3)) * 8];
        }
        __builtin_amdgcn_s_setprio(1);
        #pragma unroll
        for (int i = 0; i < 8; ++i)
            #pragma unroll
            for (int j = 0; j < 4; ++j)
                acc[i][j] = __builtin_amdgcn_mfma_f32_16x16x32_f16(af[i], bf[j], acc[i][j], 0, 0, 0);
        __builtin_amdgcn_s_setprio(0);
    }
    #undef STAGE

    // ---- epilogue ----
    #pragma unroll
    for (int i = 0; i < 8; ++i) {
        #pragma unroll
        for (int j = 0; j < 4; ++j) {
            if constexpr (MODE == 0) {
                #pragma unroll
                for (int r = 0; r < 4; ++r) {
                    const int m = m0 + wm + i*16 + g*4 + r;
                    const int n = n0 + wn + j*16 + r16;
                    outF[(size_t)m*DM + n] = acc[i][j][r];
                }
            } else {
                const int n = n0 + wn + j*16 + r16;
                const int sel = n >> 10;              // 0=q 1=k 2=v (block-uniform)
                const int cc = n & 1023;
                const int h = cc >> 6, dd = cc & 63;
                if (sel == 2) {
                    const int mb = m0 + wm + i*16 + g*4;
                    const int s0 = mb & (SEQ - 1), b = mb >> 11;
                    f16x4 pk;
                    #pragma unroll
                    for (int r = 0; r < 4; ++r) pk[r] = (_Float16)acc[i][j][r];
                    *(f16x4*)(qkv + 2*BHSD + ((size_t)((b*NH + h)*HD + dd))*SEQ + s0) = pk;
                } else {
                    #pragma unroll
                    for (int r = 0; r < 4; ++r) {
                        const int m = m0 + wm + i*16 + g*4 + r;
                        float v = acc[i][j][r];
                        float vp = __shfl_xor(v, 1);          // partner column (n^1)
                        const int s = m & (SEQ - 1), b = m >> 11;
                        float2 cs = rope[(s << 5) + (dd >> 1)];
                        float o;
                        if (dd & 1) o = vp * cs.y + v * cs.x;   // x1*sin + x2*cos
                        else        o = v * cs.x - vp * cs.y;   // x1*cos - x2*sin
                        if (sel == 0) o *= 0.18033688f;         // 1/sqrt(HD) * log2(e)
                        qkv[(size_t)sel*BHSD + ((size_t)((b*NH + h)*SEQ + s))*HD + dd] = (_Float16)o;
                    }
                }
            }
        }
    }
}

// ---------------- per-KV-tile attention step (swapped QK^T, in-register softmax) ----------
__device__ __forceinline__ void process_tile(
    const _Float16 (*__restrict__ Klb)[64], const _Float16 (*__restrict__ Vlb)[64],
    const f16x8 (&qf)[2], f32x4 (&ot)[4], float &m, float &l,
    const int Rq, const int kv0, const int g, const int r16) {

    f32x4 sT[4] = {};
    const int kchunkBase = r16 & 7;
    __builtin_amdgcn_s_setprio(1);
    #pragma unroll
    for (int ks = 0; ks < 2; ++ks) {
        #pragma unroll
        for (int n = 0; n < 4; ++n) {
            f16x8 kf = *(const f16x8*)&Klb[n*16 + r16][(((ks<<2)|g) ^ kchunkBase)*8];
            sT[n] = __builtin_amdgcn_mfma_f32_16x16x32_f16(kf, qf[ks], sT[n], 0, 0, 0);
        }
    }
    __builtin_amdgcn_s_setprio(0);

    const bool full = (kv0 + 63 <= Rq);
    float sv[16];
    if (full) {
        #pragma unroll
        for (int n = 0; n < 4; ++n)
            #pragma unroll
            for (int r = 0; r < 4; ++r) sv[n*4 + r] = sT[n][r];
    } else {
        const int q = Rq + r16;
        #pragma unroll
        for (int n = 0; n < 4; ++n)
            #pragma unroll
            for (int r = 0; r < 4; ++r)
                sv[n*4 + r] = (kv0 + n*16 + 4*g + r <= q) ? sT[n][r] : -INFINITY;
    }
    float mx = sv[0];
    #pragma unroll
    for (int i = 1; i < 16; ++i) mx = fmaxf(mx, sv[i]);
    mx = red32_max(red16_max(mx));
    const bool need = (mx > m + 8.f);
    if (__any(need)) {
        float mnew = need ? mx : m;
        float al = exp2f(m - mnew);
        m = mnew;
        l *= al;
        #pragma unroll
        for (int n = 0; n < 4; ++n) ot[n] *= al;
    }
    float ps = 0.f;
    #pragma unroll
    for (int i = 0; i < 16; ++i) { sv[i] = exp2f(sv[i] - m); ps += sv[i]; }
    l += red32_add(red16_add(ps));

    uint pk[4][2];
    #pragma unroll
    for (int t = 0; t < 4; ++t)
        #pragma unroll
        for (int rp = 0; rp < 2; ++rp) {
            union { fp16x2 h; uint u; } cv;
            cv.h = __builtin_amdgcn_cvt_pkrtz(sv[t*4 + 2*rp], sv[t*4 + 2*rp + 1]);
            pk[t][rp] = cv.u;
        }
    uint w[2][4];
    #pragma unroll
    for (int kk = 0; kk < 2; ++kk)
        #pragma unroll
        for (int rp = 0; rp < 2; ++rp) {
            u32x2 s32 = __builtin_amdgcn_permlane32_swap(pk[2*kk][rp], pk[2*kk + 1][rp], false, false);
            u32x2 s16 = __builtin_amdgcn_permlane16_swap(s32[0], s32[1], false, false);
            w[kk][rp]     = s16[0];
            w[kk][2 + rp] = s16[1];
        }

    __builtin_amdgcn_s_setprio(1);
    #pragma unroll
    for (int ks = 0; ks < 2; ++ks) {
        union { uint u[4]; f16x8 h; } pb;
        #pragma unroll
        for (int j2 = 0; j2 < 4; ++j2) pb.u[j2] = w[ks][j2];
        #pragma unroll
        for (int n = 0; n < 4; ++n) {
            f16x8 vf = *(const f16x8*)&Vlb[n*16 + r16][(((ks<<2)|g) ^ kchunkBase)*8];
            ot[n] = __builtin_amdgcn_mfma_f32_16x16x32_f16(vf, pb.h, ot[n], 0, 0, 0);
        }
    }
    __builtin_amdgcn_s_setprio(0);
}

// ---------------- flash attention: diagonal-paired 64-row q-tiles, 16 q/wave ----------------
__global__ __launch_bounds__(256, 4)
void attn_kernel(const _Float16* __restrict__ qkv, _Float16* __restrict__ ao) {
    const int tid = threadIdx.x, lane = tid & 63, w = tid >> 6;
    const int g = lane >> 4, r16 = lane & 15;
    const int bh = blockIdx.x;
    const int jq = blockIdx.y;                       // 0..15
    const int q0h = (31 - jq) * 64, q0l = jq * 64;
    const _Float16* Q   = qkv + (size_t)bh * SEQ * HD;
    const _Float16* Kp  = qkv + BHSD + (size_t)bh * SEQ * HD;
    const _Float16* Vpt = qkv + 2*BHSD + (size_t)bh * SEQ * HD;   // [d][s]

    __shared__ __align__(16) _Float16 Kl[2][64][64];
    __shared__ __align__(16) _Float16 Vl[2][64][64];

    const int rA = tid >> 3,        rB = 32 + (tid >> 3);
    const int lcA = (tid & 7) ^ (rA & 7), lcB = (tid & 7) ^ (rB & 7);
    const _Float16* KsrcA = Kp  + (size_t)rA*HD + lcA*8;
    const _Float16* KsrcB = Kp  + (size_t)rB*HD + lcB*8;
    const _Float16* VsrcA = Vpt + (size_t)rA*SEQ + lcA*8;
    const _Float16* VsrcB = Vpt + (size_t)rB*SEQ + lcB*8;

    const int Rh = q0h + w*16, Rl = q0l + w*16;
    f16x8 qfh[2], qfl[2];
    #pragma unroll
    for (int ks = 0; ks < 2; ++ks) {
        qfh[ks] = *(const f16x8*)(Q + (size_t)(Rh + r16)*HD + ks*32 + g*8);
        qfl[ks] = *(const f16x8*)(Q + (size_t)(Rl + r16)*HD + ks*32 + g*8);
    }

    f32x4 oth[4] = {}, otl[4] = {};
    float mh = -INFINITY, lh = 0.f, ml_ = -INFINITY, ll_ = 0.f;

    const int nth = (q0h >> 6) + 1;
    const int ntl = (q0l >> 6) + 1;

    #define STAGE(buf, kv0) do {                                              \
        gload_lds16(KsrcA + (size_t)(kv0)*HD, &Kl[(buf)][0][0] + tid*8);      \
        gload_lds16(KsrcB + (size_t)(kv0)*HD, &Kl[(buf)][0][0] + (256+tid)*8);\
        gload_lds16(VsrcA + (kv0),            &Vl[(buf)][0][0] + tid*8);      \
        gload_lds16(VsrcB + (kv0),            &Vl[(buf)][0][0] + (256+tid)*8);\
    } while (0)

    STAGE(0, 0);
    for (int kt = 0; kt < nth; ++kt) {
        const int kv0 = kt << 6;
        __syncthreads();
        if (kt + 1 < nth) STAGE((kt + 1) & 1, (kt + 1) << 6);
        const int buf = kt & 1;

        if (kv0 <= Rh + 15)
            process_tile(Kl[buf], Vl[buf], qfh, oth, mh, lh, Rh, kv0, g, r16);
        if (kt < ntl)
            process_tile(Kl[buf], Vl[buf], qfl, otl, ml_, ll_, Rl, kv0, g, r16);
    }
    #undef STAGE

    const int b = bh >> 4, h = bh & 15;
    const float invh = 1.0f / lh, invl = 1.0f / ll_;
    _Float16* dsth = ao + ((size_t)(b*SEQ + Rh + r16))*DM + h*HD + g*4;
    _Float16* dstl = ao + ((size_t)(b*SEQ + Rl + r16))*DM + h*HD + g*4;
    #pragma unroll
    for (int n = 0; n < 4; ++n) {
        f16x4 pkh, pkl;
        #pragma unroll
        for (int r = 0; r < 4; ++r) {
            pkh[r] = (_Float16)(oth[n][r] * invh);
            pkl[r] = (_Float16)(otl[n][r] * invl);
        }
        *(f16x4*)(dsth + n*16) = pkh;
        *(f16x4*)(dstl + n*16) = pkl;
    }
}

// ---------------- launcher ----------------
extern "C" void kernel_launch(void* const* d_in, const int* in_sizes, int n_in,
                              void* d_out, int out_size, void* d_ws, size_t ws_size,
                              hipStream_t stream) {
    const float* x  = (const float*)d_in[0];
    const int*   tp = (const int*)d_in[1];
    const float* wq = (const float*)d_in[2];
    const float* wk = (const float*)d_in[3];
    const float* wv = (const float*)d_in[4];
    const float* wo = (const float*)d_in[5];
    float* out = (float*)d_out;

    char* ws = (char*)d_ws;
    _Float16* xh  = (_Float16*)(ws);                         // 16,777,216 B
    _Float16* whq = (_Float16*)(ws + 16777216);              //  6,291,456 B (wq|wk|wv)
    _Float16* woh = (_Float16*)(ws + 23068672);              //  2,097,152 B
    _Float16* qkv = (_Float16*)(ws + 25165824);              // 50,331,648 B
    _Float16* ao  = (_Float16*)(ws + 75497472);              // 16,777,216 B
    float2*   rope= (float2*)  (ws + 92274688);              //    524,288 B  (total ~92.8 MB)

    f32_to_f16<<<MROWS*DM/1024, 256, 0, stream>>>(x, xh, MROWS*DM);
    f32_to_f16<<<DM*DM/1024, 256, 0, stream>>>(wq, whq,            DM*DM);
    f32_to_f16<<<DM*DM/1024, 256, 0, stream>>>(wk, whq + DM*DM,    DM*DM);
    f32_to_f16<<<DM*DM/1024, 256, 0, stream>>>(wv, whq + 2*DM*DM,  DM*DM);
    f32_to_f16<<<DM*DM/1024, 256, 0, stream>>>(wo, woh,            DM*DM);
    rope_table<<<SEQ*32/256, 256, 0, stream>>>(tp, rope);

    gemmT<1><<<dim3(MROWS/256, 3*DM/128), 256, 0, stream>>>(xh, whq, nullptr, qkv, rope);
    attn_kernel<<<dim3(BATCH*NH, 16), 256, 0, stream>>>(qkv, ao);
    gemmT<0><<<dim3(MROWS/256, DM/128), 256, 0, stream>>>(ao, woh, out, nullptr, nullptr);
}